// Round 4
// baseline (346.396 us; speedup 1.0000x reference)
//
#include <hip/hip_runtime.h>
#include <math.h>

#define HW 64

// f32 fast-raster record: 16 floats = 64 B (scalar dwordx16 loads)
struct FaceRasF {
  float wx0, wy0, wc0;
  float wx1, wy1, wc1;
  float wx2, wy2, wc2;
  float z0, z1, z2;
  float epsf, epsz;
  float pad0, pad1;
};

typedef unsigned long long u64;

__global__ void k_transform(const float* __restrict__ vert,
                            const float* __restrict__ rot,
                            const float* __restrict__ trans,
                            float* __restrict__ vs_cam,
                            float* __restrict__ vnorm,
                            u64* __restrict__ rowmask, int maskwords,
                            int* __restrict__ cnt,
                            int B, int V) {
  int i = blockIdx.x * blockDim.x + threadIdx.x;
  int total = gridDim.x * blockDim.x;
  // zero side buffers (replaces 2 hipMemsetAsync dispatches)
  for (int j = i; j < B * V * 3; j += total) vnorm[j] = 0.f;
  for (int j = i; j < maskwords; j += total) rowmask[j] = 0ull;
  if (i == 0) cnt[0] = 0;
  if (i >= B * V) return;
  int b = i / V;
  float x = vert[i * 3 + 0], y = vert[i * 3 + 1], z = vert[i * 3 + 2];
  const float* R = rot + b * 9;
  const float* t = trans + b * 3;
  vs_cam[i * 3 + 0] = ((x * R[0] + y * R[1]) + z * R[2]) + t[0];
  vs_cam[i * 3 + 1] = ((x * R[3] + y * R[4]) + z * R[5]) + t[1];
  vs_cam[i * 3 + 2] = ((x * R[6] + y * R[7]) + z * R[8]) + t[2];
}

__global__ void k_facepre(const float* __restrict__ vs_cam,
                          const int* __restrict__ faces,
                          FaceRasF* __restrict__ frasF,
                          u64* __restrict__ rowmask, int WPR,
                          float* __restrict__ vnorm,
                          int B, int V, int F) {
  int i = blockIdx.x * blockDim.x + threadIdx.x;
  if (i >= B * F) return;
  int b = i / F, f = i % F;
  int i0 = faces[f * 3 + 0], i1 = faces[f * 3 + 1], i2 = faces[f * 3 + 2];
  const float* c0 = vs_cam + (size_t)(b * V + i0) * 3;
  const float* c1 = vs_cam + (size_t)(b * V + i1) * 3;
  const float* c2 = vs_cam + (size_t)(b * V + i2) * 3;
  float c0x = c0[0], c0y = c0[1], c0z = c0[2];
  float c1x = c1[0], c1y = c1[1], c1z = c1[2];
  float c2x = c2[0], c2y = c2[1], c2z = c2[2];
  // f32 image coords (matches reference vs_img = xy/z in f32)
  float v0x = c0x / c0z, v0y = c0y / c0z;
  float v1x = c1x / c1z, v1y = c1y / c1z;
  float v2x = c2x / c2z, v2y = c2y / c2z;
  // f32 edge deltas (reference computes these in f32 before f64 promotion)
  float dx0 = v2x - v1x, dy0 = v2y - v1y;   // edge(v1,v2), anchor v1
  float dx1 = v0x - v2x, dy1 = v0y - v2y;   // edge(v2,v0), anchor v2
  float dx2 = v1x - v0x, dy2 = v1y - v0y;   // edge(v0,v1), anchor v0
  float A = dx2 * (v2y - v0y) - dy2 * (v2x - v0x);
  if (fabsf(A) < 1e-8f) A = 1e-8f;
  double invA = 1.0 / (double)A;
  // premultiplied barycentric coefficients: w_e = wx*px + wy*py + wc
  double wx0 = -(double)dy0 * invA, wy0 = (double)dx0 * invA;
  double wc0 = ((double)dy0 * (double)v1x - (double)dx0 * (double)v1y) * invA;
  double wx1 = -(double)dy1 * invA, wy1 = (double)dx1 * invA;
  double wc1 = ((double)dy1 * (double)v2x - (double)dx1 * (double)v2y) * invA;
  double wx2 = -(double)dy2 * invA, wy2 = (double)dx2 * invA;
  double wc2 = ((double)dy2 * (double)v0x - (double)dx2 * (double)v0y) * invA;
  double m0 = fabs(wx0) + fabs(wy0) + fabs(wc0);
  double m1 = fabs(wx1) + fabs(wy1) + fabs(wc1);
  double m2 = fabs(wx2) + fabs(wy2) + fabs(wc2);
  double mm = fmax(fmax(m0, m1), m2);
  float epsf = fmaxf((float)(6e-7 * mm), 3e-7f);  // margin over f32 eval+coeff error
  float zs = fabsf(c0z) + fabsf(c1z) + fabsf(c2z);
  float epsz = (epsf + 4e-6f) * zs;
  FaceRasF fr;
  fr.wx0 = (float)wx0; fr.wy0 = (float)wy0; fr.wc0 = (float)wc0;
  fr.wx1 = (float)wx1; fr.wy1 = (float)wy1; fr.wc1 = (float)wc1;
  fr.wx2 = (float)wx2; fr.wy2 = (float)wy2; fr.wc2 = (float)wc2;
  fr.z0 = c0z; fr.z1 = c1z; fr.z2 = c2z;
  fr.epsf = epsf; fr.epsz = epsz; fr.pad0 = 0.f; fr.pad1 = 0.f;
  frasF[i] = fr;
  // conservative y-row interval of the band-dilated triangle.
  // Face can matter to row y only if for every edge: max_x w_e = wy*y + wc + |wx| >= -band.
  // band >= prob cutoff (0.3) and >= epsf => mask is a superset of all faces that can
  // be f64-inside OR contribute to prob on this row.
  float band = fmaxf(0.302f, 1.5f * epsf);
  float ylo = -1.01f, yhi = 1.01f;
  bool empty = false;
  float wyA[3] = {fr.wy0, fr.wy1, fr.wy2};
  float gA[3]  = {fr.wc0 + fabsf(fr.wx0) + band,
                  fr.wc1 + fabsf(fr.wx1) + band,
                  fr.wc2 + fabsf(fr.wx2) + band};
#pragma unroll
  for (int e = 0; e < 3; ++e) {
    float wy = wyA[e], g = gA[e];
    if (wy > 1e-30f)       ylo = fmaxf(ylo, -g / wy);
    else if (wy < -1e-30f) yhi = fminf(yhi, -g / wy);
    else                   empty |= (g < 0.f);
    empty |= (g + fabsf(wy) < 0.f);   // box max < -band -> never active
  }
  if (!empty && ylo <= yhi) {
    int r0 = max(0, (int)floorf((ylo + 1.0f) * 31.5f) - 1);
    int r1 = min(63, (int)ceilf((yhi + 1.0f) * 31.5f) + 1);
    u64 bit = 1ull << (f & 63);
    int word = f >> 6;
    for (int r = r0; r <= r1; ++r)
      atomicOr(&rowmask[((size_t)(b * 64 + r)) * WPR + word], bit);
  }
  // face normal -> vertex normal scatter (f32 atomics)
  float e1x = c1x - c0x, e1y = c1y - c0y, e1z = c1z - c0z;
  float e2x = c2x - c0x, e2y = c2y - c0y, e2z = c2z - c0z;
  float nx = e1y * e2z - e1z * e2y;
  float ny = e1z * e2x - e1x * e2z;
  float nz = e1x * e2y - e1y * e2x;
  float* vn0 = vnorm + (size_t)(b * V + i0) * 3;
  float* vn1 = vnorm + (size_t)(b * V + i1) * 3;
  float* vn2 = vnorm + (size_t)(b * V + i2) * 3;
  atomicAdd(vn0 + 0, nx); atomicAdd(vn0 + 1, ny); atomicAdd(vn0 + 2, nz);
  atomicAdd(vn1 + 0, nx); atomicAdd(vn1 + 1, ny); atomicAdd(vn1 + 2, nz);
  atomicAdd(vn2 + 0, nx); atomicAdd(vn2 + 1, ny); atomicAdd(vn2 + 2, nz);
}

// bitmask-driven f32 screened raster: wave = one row, iterate only set bits
__global__ __launch_bounds__(256) void k_raster(
    const FaceRasF* __restrict__ frasF,
    const u64* __restrict__ rowmask, int WPR, int chunkW,
    float* __restrict__ pz, unsigned* __restrict__ pbv,
    float* __restrict__ pl, float* __restrict__ pe,
    int F, int P) {
  int b = blockIdx.x >> 4;                       // 16 blocks (of 4 rows) per image
  int rowbase = (blockIdx.x & 15) * 4;
  int wid = __builtin_amdgcn_readfirstlane(threadIdx.x >> 6);
  int row = rowbase + wid;                       // wave-uniform
  int x = threadIdx.x & 63;
  int chunk = blockIdx.y;
  const double step = 2.0 / 63.0;
  double pxd = (x == HW - 1) ? 1.0 : (x * step - 1.0);
  double pyd = (row == HW - 1) ? 1.0 : (row * step - 1.0);
  float pxf = (float)pxd, pyf = (float)pyd;
  const FaceRasF* __restrict__ fb = frasF + (size_t)b * F;
  const u64* __restrict__ rm = rowmask + ((size_t)(b * 64 + row)) * WPR + chunk * chunkW;
  int wleft = min(chunkW, WPR - chunk * chunkW);
  float zminf = INFINITY;
  float weps = 0.f;
  int best = 0;
  bool flag = false;
  float lsum = 0.f;
  for (int j = 0; j < wleft; ++j) {
    u64 m = rm[j];                               // wave-uniform scalar load
    int fbase = (chunk * chunkW + j) << 6;
    while (m) {
      int bit = __builtin_ctzll(m);
      m &= m - 1;
      int f = fbase + bit;                       // ascending face id
      const FaceRasF fr = fb[f];
      float w0 = fmaf(fr.wx0, pxf, fmaf(fr.wy0, pyf, fr.wc0));
      float w1 = fmaf(fr.wx1, pxf, fmaf(fr.wy1, pyf, fr.wc1));
      float w2 = fmaf(fr.wx2, pxf, fmaf(fr.wy2, pyf, fr.wc2));
      float dmin = fminf(fminf(w0, w1), w2);
      if (dmin > -0.3f) {
        // clip(dmin/sigma,-30,0): dmin<=-0.3 contributes ~1e-13, skipped
        float t = fminf(fmaxf(dmin * 100.0f, -30.0f), 0.0f);
        float pr = __expf(t);                    // inside -> t=0 -> pr=1 exactly
        lsum += __logf(fmaf(-pr, 0.99999990f, 1.0f));
      }
      if (dmin > -fr.epsf) {
        float z = fmaf(w2, fr.z2, fmaf(w1, fr.z1, w0 * fr.z0));
        bool contend = (z < zminf + fr.epsz + weps) & (z > -fr.epsz);
        flag |= (fabsf(dmin) < fr.epsf) & contend;           // inside-sign ambiguous
        flag |= (dmin >= 0.0f) & (fabsf(z) < fr.epsz);       // z>0 boundary ambiguous
        flag |= (dmin >= 0.0f) & (z > 0.0f) &
                (fabsf(z - zminf) < fr.epsz + weps);         // z-order ambiguous
        if ((dmin >= 0.0f) & (z > 0.0f) & (z < zminf)) {     // strict <: first-occurrence
          zminf = z; best = f; weps = fr.epsz;
        }
      }
    }
  }
  int p = b * (HW * HW) + row * HW + x;
  size_t idx = (size_t)chunk * P + p;
  pz[idx] = zminf;
  pbv[idx] = (unsigned)best | (flag ? 0x80000000u : 0u);
  pl[idx] = lsum;
  pe[idx] = weps;
}

// exact f64 winner recompute + gather-interpolate + output write (not improb)
__device__ void write_winner(const float* __restrict__ vs_cam,
                             const int* __restrict__ faces,
                             const float* __restrict__ vnorm,
                             const float* __restrict__ attribs,
                             float* __restrict__ out, int P,
                             int b, int V, int F, int pix,
                             int best, bool covered) {
  int p = b * (HW * HW) + pix;
  float imn[3] = {0.f, 0.f, 0.f};
  float ima[3] = {0.f, 0.f, 0.f};
  if (covered) {
    int x = pix & 63, y = pix >> 6;
    const double step = 2.0 / 63.0;
    double px = (x == HW - 1) ? 1.0 : (x * step - 1.0);
    double py = (y == HW - 1) ? 1.0 : (y * step - 1.0);
    int vid[3] = {faces[best * 3 + 0], faces[best * 3 + 1], faces[best * 3 + 2]};
    const float* c0 = vs_cam + (size_t)(b * V + vid[0]) * 3;
    const float* c1 = vs_cam + (size_t)(b * V + vid[1]) * 3;
    const float* c2 = vs_cam + (size_t)(b * V + vid[2]) * 3;
    float v0x = c0[0] / c0[2], v0y = c0[1] / c0[2];
    float v1x = c1[0] / c1[2], v1y = c1[1] / c1[2];
    float v2x = c2[0] / c2[2], v2y = c2[1] / c2[2];
    float dx0 = v2x - v1x, dy0 = v2y - v1y;
    float dx1 = v0x - v2x, dy1 = v0y - v2y;
    float dx2 = v1x - v0x, dy2 = v1y - v0y;
    float A = dx2 * (v2y - v0y) - dy2 * (v2x - v0x);
    if (fabsf(A) < 1e-8f) A = 1e-8f;
    double invA = 1.0 / (double)A;
    double a0 = (double)dx0 * (py - (double)v1y) - (double)dy0 * (px - (double)v1x);
    double a1 = (double)dx1 * (py - (double)v2y) - (double)dy1 * (px - (double)v2x);
    double a2 = (double)dx2 * (py - (double)v0y) - (double)dy2 * (px - (double)v0x);
    double wk[3] = {a0 * invA, a1 * invA, a2 * invA};
    double v[6] = {0, 0, 0, 0, 0, 0};
#pragma unroll
    for (int k = 0; k < 3; ++k) {
      const float* n = vnorm + (size_t)(b * V + vid[k]) * 3;
      float nx = n[0], ny = n[1], nz = n[2];
      float nrm = sqrtf(nx * nx + ny * ny + nz * nz) + 1e-10f;  // f32, like ref
      const float* at = attribs + (((size_t)(b * F + best)) * 3 + k) * 3;
      v[0] += wk[k] * (double)(nx / nrm);
      v[1] += wk[k] * (double)(ny / nrm);
      v[2] += wk[k] * (double)(nz / nrm);
      v[3] += wk[k] * (double)at[0];
      v[4] += wk[k] * (double)at[1];
      v[5] += wk[k] * (double)at[2];
    }
    double nn = sqrt(v[0] * v[0] + v[1] * v[1] + v[2] * v[2]) + 1e-10;
    imn[0] = (float)(v[0] / nn);
    imn[1] = (float)(v[1] / nn);
    imn[2] = (float)(v[2] / nn);
    ima[0] = (float)v[3]; ima[1] = (float)v[4]; ima[2] = (float)v[5];
  }
  float* o_n = out;
  float* o_a = out + (size_t)P * 3;
  float* o_p = out + (size_t)P * 6;
  float* o_i = o_p + P;
  o_n[(size_t)p * 3 + 0] = imn[0];
  o_n[(size_t)p * 3 + 1] = imn[1];
  o_n[(size_t)p * 3 + 2] = imn[2];
  o_a[(size_t)p * 3 + 0] = ima[0];
  o_a[(size_t)p * 3 + 1] = ima[1];
  o_a[(size_t)p * 3 + 2] = ima[2];
  o_i[p] = covered ? (float)best : -1.0f;
}

__global__ __launch_bounds__(64) void k_final(
    const float* __restrict__ vs_cam,
    const int* __restrict__ faces,
    const float* __restrict__ vnorm,
    const float* __restrict__ attribs,
    const float* __restrict__ pz,
    const unsigned* __restrict__ pbv,
    const float* __restrict__ pl,
    const float* __restrict__ pe,
    float* __restrict__ out,
    int* __restrict__ cnt, int* __restrict__ list,
    int B, int V, int F, int NC) {
  int p = blockIdx.x * blockDim.x + threadIdx.x;
  int P = B * HW * HW;
  if (p >= P) return;
  float zmin = INFINITY, weps = 0.f, lsum = 0.f;
  int best = 0;
  bool flag = false;
  for (int c = 0; c < NC; ++c) {   // ascending chunks: preserves first-occurrence argmin
    size_t idx = (size_t)c * P + p;
    float z = pz[idx];
    unsigned pb = pbv[idx];
    float e = pe[idx];
    flag |= (pb >> 31) != 0;
    flag |= fabsf(z - zmin) < (e + weps + 2e-6f);  // cross-chunk near-tie (NaN/INF-safe)
    if (z < zmin) { zmin = z; best = (int)(pb & 0x7fffffffu); weps = e; }
    lsum += pl[idx];
  }
  bool covered = (zmin < 1e38f);
  int b = p >> 12;            // HW*HW = 4096
  int pix = p & 4095;
  write_winner(vs_cam, faces, vnorm, attribs, out, P, b, V, F, pix, best, covered);
  float* o_p = out + (size_t)P * 6;
  o_p[p] = 1.0f - __expf(lsum);
  if (flag) {
    int s = atomicAdd(cnt, 1);
    list[s] = p;
  }
}

// exact f64 re-argmin for flagged pixels: one wave per pixel, row-masked faces only.
// Mask is a superset of f64-inside-capable faces for the row (band >= epsf).
__global__ __launch_bounds__(64) void k_repair(
    const float* __restrict__ vs_cam,
    const int* __restrict__ faces,
    const float* __restrict__ vnorm,
    const float* __restrict__ attribs,
    const u64* __restrict__ rowmask, int WPR,
    const int* __restrict__ cnt, const int* __restrict__ list,
    float* __restrict__ out, int B, int V, int F) {
  int P = B * HW * HW;
  int lane = threadIdx.x;
  int n = cnt[0];
  int WPL = (WPR + 63) >> 6;   // words per lane
  for (int i = blockIdx.x; i < n; i += gridDim.x) {
    int p = list[i];
    int b = p >> 12;
    int pix = p & 4095;
    int x = pix & 63, y = pix >> 6;
    const double step = 2.0 / 63.0;
    double px = (x == HW - 1) ? 1.0 : (x * step - 1.0);
    double py = (y == HW - 1) ? 1.0 : (y * step - 1.0);
    const u64* rm = rowmask + ((size_t)(b * 64 + y)) * WPR;
    double zmin = INFINITY;
    int best = 0x7fffffff;
    for (int k = 0; k < WPL; ++k) {
      int wi = lane * WPL + k;
      if (wi >= WPR) break;
      u64 m = rm[wi];
      while (m) {
        int bit = __builtin_ctzll(m);
        m &= m - 1;
        int f = (wi << 6) + bit;
        int i0 = faces[f * 3 + 0], i1 = faces[f * 3 + 1], i2 = faces[f * 3 + 2];
        const float* c0 = vs_cam + (size_t)(b * V + i0) * 3;
        const float* c1 = vs_cam + (size_t)(b * V + i1) * 3;
        const float* c2 = vs_cam + (size_t)(b * V + i2) * 3;
        float c0z = c0[2], c1z = c1[2], c2z = c2[2];
        float v0x = c0[0] / c0z, v0y = c0[1] / c0z;
        float v1x = c1[0] / c1z, v1y = c1[1] / c1z;
        float v2x = c2[0] / c2z, v2y = c2[1] / c2z;
        float dx0 = v2x - v1x, dy0 = v2y - v1y;
        float dx1 = v0x - v2x, dy1 = v0y - v2y;
        float dx2 = v1x - v0x, dy2 = v1y - v0y;
        float A = dx2 * (v2y - v0y) - dy2 * (v2x - v0x);
        if (fabsf(A) < 1e-8f) A = 1e-8f;
        double invA = 1.0 / (double)A;
        double a0 = (double)dx0 * (py - (double)v1y) - (double)dy0 * (px - (double)v1x);
        double a1 = (double)dx1 * (py - (double)v2y) - (double)dy1 * (px - (double)v2x);
        double a2 = (double)dx2 * (py - (double)v0y) - (double)dy2 * (px - (double)v0x);
        double w0 = a0 * invA, w1 = a1 * invA, w2 = a2 * invA;
        bool inside = (w0 >= 0.0) & (w1 >= 0.0) & (w2 >= 0.0);
        double z = (w0 * (double)c0z + w1 * (double)c1z) + w2 * (double)c2z;
        // lane-local faces ascend; ties resolved in reduce by lower idx
        if (inside & (z > 0.0) & (z < zmin)) { zmin = z; best = f; }
      }
    }
    // lexicographic (z, idx) wave reduce -> first-occurrence argmin
    for (int off = 32; off; off >>= 1) {
      double zo = __shfl_down(zmin, off);
      int bo = __shfl_down(best, off);
      if ((zo < zmin) || ((zo == zmin) && (bo < best))) { zmin = zo; best = bo; }
    }
    if (lane == 0) {
      bool covered = (zmin < 1e300);
      write_winner(vs_cam, faces, vnorm, attribs, out, P, b, V, F, pix, best, covered);
    }
  }
}

extern "C" void kernel_launch(void* const* d_in, const int* in_sizes, int n_in,
                              void* d_out, int out_size, void* d_ws, size_t ws_size,
                              hipStream_t stream) {
  const float* vert    = (const float*)d_in[0];
  const int*   faces   = (const int*)d_in[1];
  const float* attribs = (const float*)d_in[2];
  const float* rot     = (const float*)d_in[3];
  const float* trans   = (const float*)d_in[4];
  int B = in_sizes[4] / 3;
  int V = in_sizes[0] / (3 * B);
  int F = in_sizes[1] / 3;
  int P = B * HW * HW;
  int WPR = (F + 63) / 64;                 // mask words per row
  int maskwords = B * 64 * WPR;

  // chunk width (mask words per raster chunk), grown if ws is tight
  size_t fixedsz = sizeof(FaceRasF) * (size_t)B * F + 8u * (size_t)maskwords +
                   24u * (size_t)B * V + 4 + 4u * (size_t)P + 512;
  int chunkW = 4;
  while (fixedsz + (size_t)P * 16u * ((WPR + chunkW - 1) / chunkW) > ws_size &&
         chunkW < WPR) chunkW <<= 1;
  int NC = (WPR + chunkW - 1) / chunkW;

  char* w = (char*)d_ws;
  FaceRasF* frasF = (FaceRasF*)w; w += sizeof(FaceRasF) * (size_t)B * F;  // 64B-aligned
  u64* rowmask    = (u64*)w;      w += 8u * (size_t)maskwords;
  float* pz       = (float*)w;    w += sizeof(float) * (size_t)P * NC;
  unsigned* pbv   = (unsigned*)w; w += sizeof(unsigned) * (size_t)P * NC;
  float* pl       = (float*)w;    w += sizeof(float) * (size_t)P * NC;
  float* pe       = (float*)w;    w += sizeof(float) * (size_t)P * NC;
  float* vs_cam   = (float*)w;    w += sizeof(float) * 3 * (size_t)B * V;
  float* vnorm    = (float*)w;    w += sizeof(float) * 3 * (size_t)B * V;
  int* cnt        = (int*)w;      w += sizeof(int);
  int* list       = (int*)w;      w += sizeof(int) * (size_t)P;

  k_transform<<<(B * V + 255) / 256, 256, 0, stream>>>(
      vert, rot, trans, vs_cam, vnorm, rowmask, maskwords, cnt, B, V);
  k_facepre<<<(B * F + 255) / 256, 256, 0, stream>>>(
      vs_cam, faces, frasF, rowmask, WPR, vnorm, B, V, F);
  dim3 rg((unsigned)(B * 16), (unsigned)NC);
  k_raster<<<rg, 256, 0, stream>>>(frasF, rowmask, WPR, chunkW,
                                   pz, pbv, pl, pe, F, P);
  k_final<<<(P + 63) / 64, 64, 0, stream>>>(vs_cam, faces, vnorm, attribs,
                                            pz, pbv, pl, pe,
                                            (float*)d_out, cnt, list, B, V, F, NC);
  k_repair<<<256, 64, 0, stream>>>(vs_cam, faces, vnorm, attribs, rowmask, WPR,
                                   cnt, list, (float*)d_out, B, V, F);
}